// Round 2
// baseline (513.319 us; speedup 1.0000x reference)
//
#include <hip/hip_runtime.h>
#include <stdint.h>

#define N_B 8
#define A_N 131072
#define T_N 64
#define NUM_TRAIN 256
#define POS_CAP 65536
#define NEG_CAP 32768
#define NEG_TAU 0.05f
#define NB 2048
#define ITEM_CAP 1024
#define APT 8   // anchors per thread in k_main

typedef unsigned long long u64;
typedef unsigned int u32;

// ---------------- init: zero flags + counters, init column-argmax packed values ----------------
__global__ void k_init(u64* colpack, int* cnts, u32* flags32) {
    int i = blockIdx.x * blockDim.x + threadIdx.x;
    if (i < N_B * A_N / 4) flags32[i] = 0;           // 1 MB of flag bytes
    if (i < N_B * T_N)     colpack[i] = 0xFFFFFFFFull;  // pack(0, anchor 0)
    if (i < 2 * N_B)       cnts[i] = 0;
}

// IoU exactly matching the reference op sequence (no FMA contraction).
__device__ __forceinline__ float iou_one(float ay1, float ax1, float ay2, float ax2, float a_area,
                                         float gy1, float gx1, float gy2, float gx2) {
#pragma clang fp contract(off)
    float g_area = (gy2 - gy1) * (gx2 - gx1);
    float ih = fmaxf(fminf(ay2, gy2) - fmaxf(ay1, gy1), 0.0f);
    float iw = fmaxf(fminf(ax2, gx2) - fmaxf(ax1, gx1), 0.0f);
    float inter = ih * iw;
    float uni = (a_area + g_area) - inter;
    return uni > 0.0f ? inter / uni : 0.0f;
}

// ---------------- main: per-anchor row max/argmax + per-gt column argmax ----------------
// 8 anchors/thread; gt box is a wave-uniform load per column; column argmax via one
// wave shuffle-reduce + one LDS atomicMax per wave per column (vs per-thread atomics).
__global__ void __launch_bounds__(256) k_main(const float4* __restrict__ anchors4,
                                              const float4* __restrict__ gts4,
                                              float* __restrict__ iou_max,
                                              int* __restrict__ best_gt,
                                              u64* __restrict__ colpack) {
    __shared__ u64 cmax[T_N];
    int n = blockIdx.y;
    int tid = threadIdx.x;
    int lane = tid & 63;
    int a0 = blockIdx.x * (256 * APT) + tid;
    if (tid < T_N) cmax[tid] = 0xFFFFFFFFull;
    __syncthreads();

    float ay1[APT], ax1[APT], ay2[APT], ax2[APT], aar[APT];
    u64 rowp[APT];
    u32 ia[APT];
#pragma unroll
    for (int k = 0; k < APT; k++) {
        int a = a0 + k * 256;
        float4 ab = anchors4[(size_t)n * A_N + a];
        float y1 = ab.x, x1 = ab.y, y2 = ab.z, x2 = ab.w;
        bool inb = (y1 >= 0.f) && (x1 >= 0.f) && (y2 <= 1.f) && (x2 <= 1.f);
        if (!inb) { y1 = x1 = y2 = x2 = 0.f; }
        ay1[k] = y1; ax1[k] = x1; ay2[k] = y2; ax2[k] = x2;
        {
#pragma clang fp contract(off)
            aar[k] = (y2 - y1) * (x2 - x1);
        }
        rowp[k] = 0xFFFFFFFFull;   // pack(0, t=0) -> first-index fallback
        ia[k] = ~(u32)a;
    }

    for (int j = 0; j < T_N; j++) {
        float4 gb = gts4[n * T_N + j];   // uniform address -> scalar-cache load
        u64 colc = 0;                    // any pack(v, ~a) is > 0
#pragma unroll
        for (int k = 0; k < APT; k++) {
            float v = iou_one(ay1[k], ax1[k], ay2[k], ax2[k], aar[k], gb.x, gb.y, gb.z, gb.w);
            u64 pr = ((u64)__float_as_uint(v) << 32) | (u32)(~(u32)j);
            rowp[k] = pr > rowp[k] ? pr : rowp[k];
            u64 pc = ((u64)__float_as_uint(v) << 32) | ia[k];
            colc = pc > colc ? pc : colc;
        }
#pragma unroll
        for (int off = 32; off > 0; off >>= 1) {
            u64 o = (u64)__shfl_xor((unsigned long long)colc, off, 64);
            colc = o > colc ? o : colc;
        }
        if (lane == 0) atomicMax(&cmax[j], colc);
    }

#pragma unroll
    for (int k = 0; k < APT; k++) {
        int a = a0 + k * 256;
        size_t gi = (size_t)n * A_N + a;
        iou_max[gi] = __uint_as_float((u32)(rowp[k] >> 32));
        best_gt[gi] = (int)(~(u32)(rowp[k] & 0xFFFFFFFFu));
    }
    __syncthreads();
    if (tid < T_N) atomicMax(&colpack[n * T_N + tid], cmax[tid]);
}

// ---------------- mark column-winner anchors (512 scatter writes) ----------------
__global__ void k_mark(const u64* __restrict__ colpack, unsigned char* __restrict__ flags) {
    int i = blockIdx.x * blockDim.x + threadIdx.x;
    if (i < N_B * T_N) {
        int n = i >> 6;
        int a = (int)(~(u32)(colpack[i] & 0xFFFFFFFFull));
        flags[(size_t)n * A_N + a] = 1;
    }
}

// ---------------- classify + gather candidate lists (wave-aggregated atomics) ----------------
__global__ void __launch_bounds__(256) k_classify(const float* __restrict__ iou_max,
                                                  const unsigned char* __restrict__ flags,
                                                  const float* __restrict__ rpos,
                                                  const float* __restrict__ rneg,
                                                  int* __restrict__ class_tmp,
                                                  u64* __restrict__ pos_list,
                                                  u64* __restrict__ neg_list,
                                                  int* __restrict__ cnts) {
    int n = blockIdx.y;
    int tid = threadIdx.x;
    int lane = tid & 63;
    int a = blockIdx.x * 256 + tid;
    size_t gi = (size_t)n * A_N + a;
    float im = iou_max[gi];
    int c = -1;
    if (im < 0.3f) c = 0;
    if (flags[gi]) c = 1;
    if (im >= 0.7f) c = 1;
    class_tmp[gi] = c;

    bool wp = (c == 1);
    u64 mp = __ballot(wp);
    if (mp) {
        int total = __popcll(mp);
        int base = 0;
        if (lane == 0) base = atomicAdd(&cnts[n], total);
        base = __shfl(base, 0, 64);
        if (wp) {
            int i = base + __popcll(mp & ((1ull << lane) - 1));
            if (i < POS_CAP)
                pos_list[n * POS_CAP + i] = ((u64)__float_as_uint(rpos[gi]) << 32) | (u32)a;
        }
    }
    float r = rneg[gi];
    bool wn = (c == 0) && (r < NEG_TAU);
    u64 mn = __ballot(wn);
    if (mn) {
        int total = __popcll(mn);
        int base = 0;
        if (lane == 0) base = atomicAdd(&cnts[N_B + n], total);
        base = __shfl(base, 0, 64);
        if (wn) {
            int i = base + __popcll(mn & ((1ull << lane) - 1));
            if (i < NEG_CAP)
                neg_list[n * NEG_CAP + i] = ((u64)__float_as_uint(r) << 32) | (u32)a;
        }
    }
}

// ---------------- exact k-th smallest packed value (block-cooperative) ----------------
__device__ u64 select_kth(const u64* list, int cnt, int k, float scale, u64 overflow_cutoff,
                          int* hist, int* csum, u64* items, int* misc, u64* result) {
    int tid = threadIdx.x;
    if (k >= cnt) return overflow_cutoff;  // uniform

    for (int i = tid; i < NB; i += 256) hist[i] = 0;
    if (tid == 0) { misc[0] = -1; misc[1] = 0; misc[2] = 0; *result = overflow_cutoff; }
    __syncthreads();

    for (int i = tid; i < cnt; i += 256) {
        float v = __uint_as_float((u32)(list[i] >> 32));
        int b = (int)(v * scale); b = b < NB - 1 ? b : NB - 1;
        atomicAdd(&hist[b], 1);
    }
    __syncthreads();

    int base = tid * (NB / 256);
    int s = 0;
#pragma unroll
    for (int j = 0; j < NB / 256; j++) s += hist[base + j];
    csum[tid] = s;
    __syncthreads();
    if (tid == 0) {
        int run = 0;
        for (int j = 0; j < 256; j++) { int t = csum[j]; csum[j] = run; run += t; }
    }
    __syncthreads();
    int run = csum[tid];
#pragma unroll
    for (int j = 0; j < NB / 256; j++) {
        int h = hist[base + j];
        if (k >= run && k < run + h) { misc[0] = base + j; misc[1] = run; }
        run += h;
    }
    __syncthreads();
    int b = misc[0], before = misc[1];

    for (int i = tid; i < cnt; i += 256) {
        u64 p = list[i];
        float v = __uint_as_float((u32)(p >> 32));
        int bb = (int)(v * scale); bb = bb < NB - 1 ? bb : NB - 1;
        if (bb == b) { int ix = atomicAdd(&misc[2], 1); if (ix < ITEM_CAP) items[ix] = p; }
    }
    __syncthreads();
    int m = misc[2]; m = m < ITEM_CAP ? m : ITEM_CAP;
    int target = k - before;
    for (int i = tid; i < m; i += 256) {
        u64 p = items[i];
        int r = 0;
        for (int j = 0; j < m; j++) r += (items[j] < p);
        if (r == target) *result = p;
    }
    __syncthreads();
    u64 res = *result;
    __syncthreads();
    return res;
}

__global__ void k_select(const u64* __restrict__ pos_list, const u64* __restrict__ neg_list,
                         const int* __restrict__ cnts, u64* __restrict__ cutoff) {
    __shared__ int hist[NB];
    __shared__ int csum[256];
    __shared__ u64 items[ITEM_CAP];
    __shared__ int misc[4];
    __shared__ u64 result;
    int n = blockIdx.x;
    int P = cnts[n];
    int C = cnts[N_B + n];
    int Pc = P < POS_CAP ? P : POS_CAP;
    int Cc = C < NEG_CAP ? C : NEG_CAP;

    u64 cpos = select_kth(pos_list + n * POS_CAP, Pc, NUM_TRAIN / 2, (float)NB,
                          0xFFFFFFFFFFFFFFFFull, hist, csum, items, misc, &result);
    int n_pos = P < NUM_TRAIN / 2 ? P : NUM_TRAIN / 2;
    int k_neg = NUM_TRAIN - n_pos;
    u64 cneg = select_kth(neg_list + n * NEG_CAP, Cc, k_neg, (float)NB / NEG_TAU,
                          ((u64)__float_as_uint(NEG_TAU) << 32), hist, csum, items, misc, &result);
    if (threadIdx.x == 0) { cutoff[2 * n] = cpos; cutoff[2 * n + 1] = cneg; }
}

// ---------------- final: subsample decision + deltas + output ----------------
__global__ void k_final(const float* __restrict__ anchors, const float* __restrict__ gts,
                        const int* __restrict__ class_tmp, const int* __restrict__ best_gt,
                        const float* __restrict__ rpos, const float* __restrict__ rneg,
                        const u64* __restrict__ cutoff,
                        float* __restrict__ out_classes, float4* __restrict__ out_deltas) {
    __shared__ float g[T_N * 4];
    int n = blockIdx.y;
    int tid = threadIdx.x;
    int a = blockIdx.x * 256 + tid;
    g[tid] = gts[n * T_N * 4 + tid];
    __syncthreads();

    size_t gi = (size_t)n * A_N + a;
    int c = class_tmp[gi];
    int fc = -1;
    if (c == 1) {
        u64 p = ((u64)__float_as_uint(rpos[gi]) << 32) | (u32)a;
        fc = (p < cutoff[2 * n]) ? 1 : -1;
    } else if (c == 0) {
        u64 p = ((u64)__float_as_uint(rneg[gi]) << 32) | (u32)a;
        fc = (p < cutoff[2 * n + 1]) ? 0 : -1;
    }
    out_classes[gi] = (float)fc;

    float4 d = make_float4(0.f, 0.f, 0.f, 0.f);
    if (fc == 1) {
        float4 ab = reinterpret_cast<const float4*>(anchors)[gi];
        float ay1 = ab.x, ax1 = ab.y, ay2 = ab.z, ax2 = ab.w;
        bool inb = (ay1 >= 0.f) && (ax1 >= 0.f) && (ay2 <= 1.f) && (ax2 <= 1.f);
        if (!inb) { ay1 = ax1 = ay2 = ax2 = 0.f; }
        int bg = best_gt[gi];
        float gy1 = g[bg * 4 + 0], gx1 = g[bg * 4 + 1], gy2 = g[bg * 4 + 2], gx2 = g[bg * 4 + 3];
        float ah = ay2 - ay1, aw = ax2 - ax1;
        float acy = ay1 + 0.5f * ah, acx = ax1 + 0.5f * aw;
        float gh = gy2 - gy1, gw = gx2 - gx1;
        float gcy = gy1 + 0.5f * gh, gcx = gx1 + 0.5f * gw;
        float ah_s = ah > 0.f ? ah : 1.f, aw_s = aw > 0.f ? aw : 1.f;
        float gh_s = gh > 0.f ? gh : 1.f, gw_s = gw > 0.f ? gw : 1.f;
        d.x = (gcy - acy) / ah_s;
        d.y = (gcx - acx) / aw_s;
        d.z = logf(gh_s / ah_s);
        d.w = logf(gw_s / aw_s);
    }
    out_deltas[gi] = d;
}

extern "C" void kernel_launch(void* const* d_in, const int* in_sizes, int n_in,
                              void* d_out, int out_size, void* d_ws, size_t ws_size,
                              hipStream_t stream) {
    const float* anchors = (const float*)d_in[0];
    const float* gts     = (const float*)d_in[1];
    const float* rpos    = (const float*)d_in[2];
    const float* rneg    = (const float*)d_in[3];

    char* p = (char*)d_ws;
    u64* cutoff   = (u64*)p;  p += 2 * N_B * sizeof(u64);
    u64* colpack  = (u64*)p;  p += N_B * T_N * sizeof(u64);
    u64* pos_list = (u64*)p;  p += (size_t)N_B * POS_CAP * sizeof(u64);
    u64* neg_list = (u64*)p;  p += (size_t)N_B * NEG_CAP * sizeof(u64);
    float* iou_max = (float*)p; p += (size_t)N_B * A_N * sizeof(float);
    int* best_gt   = (int*)p;   p += (size_t)N_B * A_N * sizeof(int);
    int* class_tmp = (int*)p;   p += (size_t)N_B * A_N * sizeof(int);
    int* cnts      = (int*)p;   p += 2 * N_B * sizeof(int);
    unsigned char* flags = (unsigned char*)p; p += (size_t)N_B * A_N;

    float* out_classes = (float*)d_out;
    float4* out_deltas = (float4*)(out_classes + (size_t)N_B * A_N);

    k_init<<<N_B * A_N / 4 / 256, 256, 0, stream>>>(colpack, cnts, (u32*)flags);
    k_main<<<dim3(A_N / (256 * APT), N_B), 256, 0, stream>>>(
        (const float4*)anchors, (const float4*)gts, iou_max, best_gt, colpack);
    k_mark<<<2, 256, 0, stream>>>(colpack, flags);
    k_classify<<<dim3(A_N / 256, N_B), 256, 0, stream>>>(iou_max, flags, rpos, rneg,
                                                         class_tmp, pos_list, neg_list, cnts);
    k_select<<<N_B, 256, 0, stream>>>(pos_list, neg_list, cnts, cutoff);
    k_final<<<dim3(A_N / 256, N_B), 256, 0, stream>>>(anchors, gts, class_tmp, best_gt,
                                                      rpos, rneg, cutoff, out_classes, out_deltas);
}

// Round 3
// 212.793 us; speedup vs baseline: 2.4123x; 2.4123x over previous
//
#include <hip/hip_runtime.h>
#include <stdint.h>

#define N_B 8
#define A_N 131072
#define T_N 64
#define NUM_TRAIN 256
#define POS_CAP 65536
#define NEG_CAP 32768
#define NEG_TAU 0.05f
#define NB 2048
#define ITEM_CAP 1024
#define APT 8           // anchors per thread in k_main
#define CPT 4           // anchors per thread in classify/gather
#define BLK_C (A_N / (256 * CPT))   // 128 blocks per batch in classify/gather

typedef unsigned long long u64;
typedef unsigned int u32;

// ---------------- init: zero flags, init column-argmax packed values ----------------
__global__ void k_init(u64* colpack, u32* flags32) {
    int i = blockIdx.x * blockDim.x + threadIdx.x;
    if (i < N_B * A_N / 4) flags32[i] = 0;              // 1 MB of flag bytes
    if (i < N_B * T_N)     colpack[i] = 0xFFFFFFFFull;  // pack(0, anchor 0)
}

// IoU exactly matching the reference op sequence (no FMA contraction).
__device__ __forceinline__ float iou_one(float ay1, float ax1, float ay2, float ax2, float a_area,
                                         float gy1, float gx1, float gy2, float gx2) {
#pragma clang fp contract(off)
    float g_area = (gy2 - gy1) * (gx2 - gx1);
    float ih = fmaxf(fminf(ay2, gy2) - fmaxf(ay1, gy1), 0.0f);
    float iw = fmaxf(fminf(ax2, gx2) - fmaxf(ax1, gx1), 0.0f);
    float inter = ih * iw;
    float uni = (a_area + g_area) - inter;
    return uni > 0.0f ? inter / uni : 0.0f;
}

// ---------------- main: per-anchor row max/argmax + per-gt column argmax ----------------
__global__ void __launch_bounds__(256) k_main(const float4* __restrict__ anchors4,
                                              const float4* __restrict__ gts4,
                                              float* __restrict__ iou_max,
                                              int* __restrict__ best_gt,
                                              u64* __restrict__ colpack) {
    __shared__ u64 cmax[T_N];
    int n = blockIdx.y;
    int tid = threadIdx.x;
    int lane = tid & 63;
    int a0 = blockIdx.x * (256 * APT) + tid;
    if (tid < T_N) cmax[tid] = 0xFFFFFFFFull;
    __syncthreads();

    float ay1[APT], ax1[APT], ay2[APT], ax2[APT], aar[APT];
    u64 rowp[APT];
    u32 ia[APT];
#pragma unroll
    for (int k = 0; k < APT; k++) {
        int a = a0 + k * 256;
        float4 ab = anchors4[(size_t)n * A_N + a];
        float y1 = ab.x, x1 = ab.y, y2 = ab.z, x2 = ab.w;
        bool inb = (y1 >= 0.f) && (x1 >= 0.f) && (y2 <= 1.f) && (x2 <= 1.f);
        if (!inb) { y1 = x1 = y2 = x2 = 0.f; }
        ay1[k] = y1; ax1[k] = x1; ay2[k] = y2; ax2[k] = x2;
        {
#pragma clang fp contract(off)
            aar[k] = (y2 - y1) * (x2 - x1);
        }
        rowp[k] = 0xFFFFFFFFull;   // pack(0, t=0) -> first-index fallback
        ia[k] = ~(u32)a;
    }

    for (int j = 0; j < T_N; j++) {
        float4 gb = gts4[n * T_N + j];   // uniform address -> scalar-cache load
        u64 colc = 0;                    // any pack(v, ~a) is > 0
#pragma unroll
        for (int k = 0; k < APT; k++) {
            float v = iou_one(ay1[k], ax1[k], ay2[k], ax2[k], aar[k], gb.x, gb.y, gb.z, gb.w);
            u64 pr = ((u64)__float_as_uint(v) << 32) | (u32)(~(u32)j);
            rowp[k] = pr > rowp[k] ? pr : rowp[k];
            u64 pc = ((u64)__float_as_uint(v) << 32) | ia[k];
            colc = pc > colc ? pc : colc;
        }
#pragma unroll
        for (int off = 32; off > 0; off >>= 1) {
            u64 o = (u64)__shfl_xor((unsigned long long)colc, off, 64);
            colc = o > colc ? o : colc;
        }
        if (lane == 0) atomicMax(&cmax[j], colc);
    }

#pragma unroll
    for (int k = 0; k < APT; k++) {
        int a = a0 + k * 256;
        size_t gi = (size_t)n * A_N + a;
        iou_max[gi] = __uint_as_float((u32)(rowp[k] >> 32));
        best_gt[gi] = (int)(~(u32)(rowp[k] & 0xFFFFFFFFu));
    }
    __syncthreads();
    if (tid < T_N) atomicMax(&colpack[n * T_N + tid], cmax[tid]);
}

// ---------------- mark column-winner anchors (512 scatter writes) ----------------
__global__ void k_mark(const u64* __restrict__ colpack, unsigned char* __restrict__ flags) {
    int i = blockIdx.x * blockDim.x + threadIdx.x;
    if (i < N_B * T_N) {
        int n = i >> 6;
        int a = (int)(~(u32)(colpack[i] & 0xFFFFFFFFull));
        flags[(size_t)n * A_N + a] = 1;
    }
}

// ---------------- classify: class bytes + per-block candidate counts (NO global atomics) ------
__global__ void __launch_bounds__(256) k_classify(const float4* __restrict__ iou_max4,
                                                  const u32* __restrict__ flags32,
                                                  const float4* __restrict__ rneg4,
                                                  u32* __restrict__ class32,
                                                  int* __restrict__ bcp, int* __restrict__ bcn) {
    int n = blockIdx.y;
    int bx = blockIdx.x;
    int tid = threadIdx.x;
    size_t gi4 = ((size_t)n * A_N) / 4 + bx * 256 + tid;
    float4 im = iou_max4[gi4];
    u32 fl = flags32[gi4];
    float4 rn = rneg4[gi4];

    float imv[4] = {im.x, im.y, im.z, im.w};
    float rnv[4] = {rn.x, rn.y, rn.z, rn.w};
    int pcnt = 0, ncnt = 0;
    u32 cw = 0;
#pragma unroll
    for (int j = 0; j < 4; j++) {
        int c = -1;
        if (imv[j] < 0.3f) c = 0;
        if ((fl >> (8 * j)) & 0xFF) c = 1;
        if (imv[j] >= 0.7f) c = 1;
        cw |= ((u32)(unsigned char)(signed char)c) << (8 * j);
        pcnt += (c == 1);
        ncnt += (c == 0 && rnv[j] < NEG_TAU);
    }
    class32[gi4] = cw;

#pragma unroll
    for (int off = 32; off > 0; off >>= 1) {
        pcnt += __shfl_xor(pcnt, off, 64);
        ncnt += __shfl_xor(ncnt, off, 64);
    }
    __shared__ int wp[4], wn[4];
    if ((tid & 63) == 0) { wp[tid >> 6] = pcnt; wn[tid >> 6] = ncnt; }
    __syncthreads();
    if (tid == 0) {
        bcp[n * BLK_C + bx] = wp[0] + wp[1] + wp[2] + wp[3];
        bcn[n * BLK_C + bx] = wn[0] + wn[1] + wn[2] + wn[3];
    }
}

// ---------------- scan: per-batch exclusive scan of block counts ----------------
__global__ void k_scan(const int* __restrict__ bcp, const int* __restrict__ bcn,
                       int* __restrict__ bop, int* __restrict__ bon, int* __restrict__ cnts) {
    __shared__ int s[BLK_C];
    int n = blockIdx.x;
    int t = threadIdx.x;

    int v = bcp[n * BLK_C + t];
    s[t] = v; __syncthreads();
    for (int d = 1; d < BLK_C; d <<= 1) {
        int x = (t >= d) ? s[t - d] : 0;
        __syncthreads();
        s[t] += x;
        __syncthreads();
    }
    bop[n * BLK_C + t] = s[t] - v;
    if (t == BLK_C - 1) cnts[n] = s[BLK_C - 1];
    __syncthreads();

    v = bcn[n * BLK_C + t];
    s[t] = v; __syncthreads();
    for (int d = 1; d < BLK_C; d <<= 1) {
        int x = (t >= d) ? s[t - d] : 0;
        __syncthreads();
        s[t] += x;
        __syncthreads();
    }
    bon[n * BLK_C + t] = s[t] - v;
    if (t == BLK_C - 1) cnts[N_B + n] = s[BLK_C - 1];
}

// ---------------- gather: dense candidate lists via block offsets + LDS slots ----------------
__global__ void __launch_bounds__(256) k_gather(const u32* __restrict__ class32,
                                                const float4* __restrict__ rpos4,
                                                const float4* __restrict__ rneg4,
                                                const int* __restrict__ bop,
                                                const int* __restrict__ bon,
                                                u64* __restrict__ pos_list,
                                                u64* __restrict__ neg_list) {
    __shared__ int lp, ln;
    int n = blockIdx.y;
    int bx = blockIdx.x;
    int tid = threadIdx.x;
    if (tid == 0) { lp = 0; ln = 0; }
    __syncthreads();

    size_t gi4 = ((size_t)n * A_N) / 4 + bx * 256 + tid;
    u32 cw = class32[gi4];
    float4 rp = rpos4[gi4];
    float4 rn = rneg4[gi4];
    float rpv[4] = {rp.x, rp.y, rp.z, rp.w};
    float rnv[4] = {rn.x, rn.y, rn.z, rn.w};
    int a0 = (bx * 256 + tid) * 4;
    int bp = bop[n * BLK_C + bx];
    int bn = bon[n * BLK_C + bx];

#pragma unroll
    for (int j = 0; j < 4; j++) {
        int c = (int)(signed char)((cw >> (8 * j)) & 0xFF);
        int a = a0 + j;
        if (c == 1) {
            int slot = atomicAdd(&lp, 1);
            int i = bp + slot;
            if (i < POS_CAP)
                pos_list[n * POS_CAP + i] = ((u64)__float_as_uint(rpv[j]) << 32) | (u32)a;
        } else if (c == 0 && rnv[j] < NEG_TAU) {
            int slot = atomicAdd(&ln, 1);
            int i = bn + slot;
            if (i < NEG_CAP)
                neg_list[n * NEG_CAP + i] = ((u64)__float_as_uint(rnv[j]) << 32) | (u32)a;
        }
    }
}

// ---------------- exact k-th smallest packed value (block-cooperative) ----------------
__device__ u64 select_kth(const u64* list, int cnt, int k, float scale, u64 overflow_cutoff,
                          int* hist, int* csum, u64* items, int* misc, u64* result) {
    int tid = threadIdx.x;
    if (k >= cnt) return overflow_cutoff;  // uniform

    for (int i = tid; i < NB; i += 256) hist[i] = 0;
    if (tid == 0) { misc[0] = -1; misc[1] = 0; misc[2] = 0; *result = overflow_cutoff; }
    __syncthreads();

    for (int i = tid; i < cnt; i += 256) {
        float v = __uint_as_float((u32)(list[i] >> 32));
        int b = (int)(v * scale); b = b < NB - 1 ? b : NB - 1;
        atomicAdd(&hist[b], 1);
    }
    __syncthreads();

    int base = tid * (NB / 256);
    int s = 0;
#pragma unroll
    for (int j = 0; j < NB / 256; j++) s += hist[base + j];
    csum[tid] = s;
    __syncthreads();
    if (tid == 0) {
        int run = 0;
        for (int j = 0; j < 256; j++) { int t = csum[j]; csum[j] = run; run += t; }
    }
    __syncthreads();
    int run = csum[tid];
#pragma unroll
    for (int j = 0; j < NB / 256; j++) {
        int h = hist[base + j];
        if (k >= run && k < run + h) { misc[0] = base + j; misc[1] = run; }
        run += h;
    }
    __syncthreads();
    int b = misc[0], before = misc[1];

    for (int i = tid; i < cnt; i += 256) {
        u64 p = list[i];
        float v = __uint_as_float((u32)(p >> 32));
        int bb = (int)(v * scale); bb = bb < NB - 1 ? bb : NB - 1;
        if (bb == b) { int ix = atomicAdd(&misc[2], 1); if (ix < ITEM_CAP) items[ix] = p; }
    }
    __syncthreads();
    int m = misc[2]; m = m < ITEM_CAP ? m : ITEM_CAP;
    int target = k - before;
    for (int i = tid; i < m; i += 256) {
        u64 p = items[i];
        int r = 0;
        for (int j = 0; j < m; j++) r += (items[j] < p);
        if (r == target) *result = p;
    }
    __syncthreads();
    u64 res = *result;
    __syncthreads();
    return res;
}

__global__ void k_select(const u64* __restrict__ pos_list, const u64* __restrict__ neg_list,
                         const int* __restrict__ cnts, u64* __restrict__ cutoff) {
    __shared__ int hist[NB];
    __shared__ int csum[256];
    __shared__ u64 items[ITEM_CAP];
    __shared__ int misc[4];
    __shared__ u64 result;
    int n = blockIdx.x;
    int P = cnts[n];
    int C = cnts[N_B + n];
    int Pc = P < POS_CAP ? P : POS_CAP;
    int Cc = C < NEG_CAP ? C : NEG_CAP;

    u64 cpos = select_kth(pos_list + n * POS_CAP, Pc, NUM_TRAIN / 2, (float)NB,
                          0xFFFFFFFFFFFFFFFFull, hist, csum, items, misc, &result);
    int n_pos = P < NUM_TRAIN / 2 ? P : NUM_TRAIN / 2;
    int k_neg = NUM_TRAIN - n_pos;
    u64 cneg = select_kth(neg_list + n * NEG_CAP, Cc, k_neg, (float)NB / NEG_TAU,
                          ((u64)__float_as_uint(NEG_TAU) << 32), hist, csum, items, misc, &result);
    if (threadIdx.x == 0) { cutoff[2 * n] = cpos; cutoff[2 * n + 1] = cneg; }
}

// ---------------- final: subsample decision + deltas + output ----------------
__global__ void k_final(const float* __restrict__ anchors, const float* __restrict__ gts,
                        const signed char* __restrict__ cls, const int* __restrict__ best_gt,
                        const float* __restrict__ rpos, const float* __restrict__ rneg,
                        const u64* __restrict__ cutoff,
                        float* __restrict__ out_classes, float4* __restrict__ out_deltas) {
    __shared__ float g[T_N * 4];
    int n = blockIdx.y;
    int tid = threadIdx.x;
    int a = blockIdx.x * 256 + tid;
    g[tid] = gts[n * T_N * 4 + tid];
    __syncthreads();

    size_t gi = (size_t)n * A_N + a;
    int c = cls[gi];
    int fc = -1;
    if (c == 1) {
        u64 p = ((u64)__float_as_uint(rpos[gi]) << 32) | (u32)a;
        fc = (p < cutoff[2 * n]) ? 1 : -1;
    } else if (c == 0) {
        u64 p = ((u64)__float_as_uint(rneg[gi]) << 32) | (u32)a;
        fc = (p < cutoff[2 * n + 1]) ? 0 : -1;
    }
    out_classes[gi] = (float)fc;

    float4 d = make_float4(0.f, 0.f, 0.f, 0.f);
    if (fc == 1) {
        float4 ab = reinterpret_cast<const float4*>(anchors)[gi];
        float ay1 = ab.x, ax1 = ab.y, ay2 = ab.z, ax2 = ab.w;
        bool inb = (ay1 >= 0.f) && (ax1 >= 0.f) && (ay2 <= 1.f) && (ax2 <= 1.f);
        if (!inb) { ay1 = ax1 = ay2 = ax2 = 0.f; }
        int bg = best_gt[gi];
        float gy1 = g[bg * 4 + 0], gx1 = g[bg * 4 + 1], gy2 = g[bg * 4 + 2], gx2 = g[bg * 4 + 3];
        float ah = ay2 - ay1, aw = ax2 - ax1;
        float acy = ay1 + 0.5f * ah, acx = ax1 + 0.5f * aw;
        float gh = gy2 - gy1, gw = gx2 - gx1;
        float gcy = gy1 + 0.5f * gh, gcx = gx1 + 0.5f * gw;
        float ah_s = ah > 0.f ? ah : 1.f, aw_s = aw > 0.f ? aw : 1.f;
        float gh_s = gh > 0.f ? gh : 1.f, gw_s = gw > 0.f ? gw : 1.f;
        d.x = (gcy - acy) / ah_s;
        d.y = (gcx - acx) / aw_s;
        d.z = logf(gh_s / ah_s);
        d.w = logf(gw_s / aw_s);
    }
    out_deltas[gi] = d;
}

extern "C" void kernel_launch(void* const* d_in, const int* in_sizes, int n_in,
                              void* d_out, int out_size, void* d_ws, size_t ws_size,
                              hipStream_t stream) {
    const float* anchors = (const float*)d_in[0];
    const float* gts     = (const float*)d_in[1];
    const float* rpos    = (const float*)d_in[2];
    const float* rneg    = (const float*)d_in[3];

    char* p = (char*)d_ws;
    u64* cutoff   = (u64*)p;  p += 2 * N_B * sizeof(u64);
    u64* colpack  = (u64*)p;  p += N_B * T_N * sizeof(u64);
    u64* pos_list = (u64*)p;  p += (size_t)N_B * POS_CAP * sizeof(u64);
    u64* neg_list = (u64*)p;  p += (size_t)N_B * NEG_CAP * sizeof(u64);
    float* iou_max = (float*)p; p += (size_t)N_B * A_N * sizeof(float);
    int* best_gt   = (int*)p;   p += (size_t)N_B * A_N * sizeof(int);
    signed char* class_tmp = (signed char*)p; p += (size_t)N_B * A_N;   // 1 MB bytes
    int* cnts = (int*)p;  p += 2 * N_B * sizeof(int);
    int* bcp  = (int*)p;  p += N_B * BLK_C * sizeof(int);
    int* bcn  = (int*)p;  p += N_B * BLK_C * sizeof(int);
    int* bop  = (int*)p;  p += N_B * BLK_C * sizeof(int);
    int* bon  = (int*)p;  p += N_B * BLK_C * sizeof(int);
    unsigned char* flags = (unsigned char*)p; p += (size_t)N_B * A_N;

    float* out_classes = (float*)d_out;
    float4* out_deltas = (float4*)(out_classes + (size_t)N_B * A_N);

    k_init<<<N_B * A_N / 4 / 256, 256, 0, stream>>>(colpack, (u32*)flags);
    k_main<<<dim3(A_N / (256 * APT), N_B), 256, 0, stream>>>(
        (const float4*)anchors, (const float4*)gts, iou_max, best_gt, colpack);
    k_mark<<<2, 256, 0, stream>>>(colpack, flags);
    k_classify<<<dim3(BLK_C, N_B), 256, 0, stream>>>(
        (const float4*)iou_max, (const u32*)flags, (const float4*)rneg,
        (u32*)class_tmp, bcp, bcn);
    k_scan<<<N_B, BLK_C, 0, stream>>>(bcp, bcn, bop, bon, cnts);
    k_gather<<<dim3(BLK_C, N_B), 256, 0, stream>>>(
        (const u32*)class_tmp, (const float4*)rpos, (const float4*)rneg,
        bop, bon, pos_list, neg_list);
    k_select<<<N_B, 256, 0, stream>>>(pos_list, neg_list, cnts, cutoff);
    k_final<<<dim3(A_N / 256, N_B), 256, 0, stream>>>(anchors, gts, class_tmp, best_gt,
                                                      rpos, rneg, cutoff, out_classes, out_deltas);
}

// Round 4
// 212.053 us; speedup vs baseline: 2.4207x; 1.0035x over previous
//
#include <hip/hip_runtime.h>
#include <stdint.h>

#define N_B 8
#define A_N 131072
#define T_N 64
#define NUM_TRAIN 256
#define POS_CAP 65536
#define NEG_CAP 32768
#define NEG_TAU 0.05f
#define NB 2048
#define ITEM_CAP 1024
#define APT 4                         // anchors per thread in k_main
#define GBLK (A_N / (256 * APT))      // 128 k_main blocks per batch
#define CPT 4                         // anchors per thread in classify/gather/final
#define BLK_C (A_N / (256 * CPT))     // 128 blocks per batch

typedef unsigned long long u64;
typedef unsigned int u32;

// IoU exactly matching the reference op sequence (no FMA contraction).
// g_area precomputed once per gt (bit-identical: same formula, deterministic).
__device__ __forceinline__ float iou_one(float ay1, float ax1, float ay2, float ax2, float a_area,
                                         float gy1, float gx1, float gy2, float gx2, float g_area) {
#pragma clang fp contract(off)
    float ih = fmaxf(fminf(ay2, gy2) - fmaxf(ay1, gy1), 0.0f);
    float iw = fmaxf(fminf(ax2, gx2) - fmaxf(ax1, gx1), 0.0f);
    float inter = ih * iw;
    float uni = (a_area + g_area) - inter;
    return uni > 0.0f ? inter / uni : 0.0f;
}

// ---------------- main: per-anchor row max/argmax + per-gt per-block column argmax ------------
// APT=4 + launch_bounds(256,4): ~60 live VGPRs, NO scratch spill (round-3 bug: APT=8 @ 56 VGPR
// spilled 16.7 GB). Column partials go to per-block slots -> no init kernel, no global atomics.
__global__ void __launch_bounds__(256, 4) k_main(const float4* __restrict__ anchors4,
                                                 const float4* __restrict__ gts4,
                                                 float* __restrict__ iou_max,
                                                 int* __restrict__ best_gt,
                                                 u64* __restrict__ colpart) {
    __shared__ float gy1s[T_N], gx1s[T_N], gy2s[T_N], gx2s[T_N], gars[T_N];
    __shared__ u64 cmax[T_N];
    int n = blockIdx.y;
    int tid = threadIdx.x;
    int lane = tid & 63;
    int a0 = blockIdx.x * (256 * APT) + tid;

    if (tid < T_N) {
        float4 gb = gts4[n * T_N + tid];
        gy1s[tid] = gb.x; gx1s[tid] = gb.y; gy2s[tid] = gb.z; gx2s[tid] = gb.w;
        {
#pragma clang fp contract(off)
            gars[tid] = (gb.z - gb.x) * (gb.w - gb.y);
        }
        cmax[tid] = 0;   // every pc=(v<<32)|~a is > 0, so 0 is a safe identity
    }
    __syncthreads();

    float ay1[APT], ax1[APT], ay2[APT], ax2[APT], aar[APT];
    u64 rowp[APT];
#pragma unroll
    for (int k = 0; k < APT; k++) {
        float4 ab = anchors4[(size_t)n * A_N + a0 + k * 256];
        float y1 = ab.x, x1 = ab.y, y2 = ab.z, x2 = ab.w;
        bool inb = (y1 >= 0.f) && (x1 >= 0.f) && (y2 <= 1.f) && (x2 <= 1.f);
        if (!inb) { y1 = x1 = y2 = x2 = 0.f; }
        ay1[k] = y1; ax1[k] = x1; ay2[k] = y2; ax2[k] = x2;
        {
#pragma clang fp contract(off)
            aar[k] = (y2 - y1) * (x2 - x1);
        }
        rowp[k] = 0xFFFFFFFFull;   // pack(0, t=0) -> first-index fallback
    }

#pragma unroll 2
    for (int j = 0; j < T_N; j++) {
        float gy1 = gy1s[j], gx1 = gx1s[j], gy2 = gy2s[j], gx2 = gx2s[j], gar = gars[j];
        u64 colc = 0;
#pragma unroll
        for (int k = 0; k < APT; k++) {
            float v = iou_one(ay1[k], ax1[k], ay2[k], ax2[k], aar[k], gy1, gx1, gy2, gx2, gar);
            u64 pr = ((u64)__float_as_uint(v) << 32) | (u32)(~(u32)j);
            rowp[k] = pr > rowp[k] ? pr : rowp[k];
            u64 pc = ((u64)__float_as_uint(v) << 32) | (u32)(~(u32)(a0 + k * 256));
            colc = pc > colc ? pc : colc;
        }
#pragma unroll
        for (int off = 32; off > 0; off >>= 1) {
            u64 o = (u64)__shfl_xor((unsigned long long)colc, off, 64);
            colc = o > colc ? o : colc;
        }
        if (lane == 0) atomicMax(&cmax[j], colc);
    }

#pragma unroll
    for (int k = 0; k < APT; k++) {
        size_t gi = (size_t)n * A_N + a0 + k * 256;
        iou_max[gi] = __uint_as_float((u32)(rowp[k] >> 32));
        best_gt[gi] = (int)(~(u32)(rowp[k] & 0xFFFFFFFFu));
    }
    __syncthreads();
    if (tid < T_N) colpart[((size_t)n * T_N + tid) * GBLK + blockIdx.x] = cmax[tid];
}

// ---------------- reduce per-block column partials -> global winners ----------------
__global__ void k_colred(const u64* __restrict__ colpart, u64* __restrict__ colred) {
    int i = blockIdx.x * blockDim.x + threadIdx.x;
    if (i < N_B * T_N) {
        const u64* p = colpart + (size_t)i * GBLK;
        u64 m = 0;
        for (int b = 0; b < GBLK; b++) { u64 v = p[b]; m = v > m ? v : m; }
        colred[i] = m;
    }
}

// ---------------- classify: class bytes + per-block candidate counts ----------------
__global__ void __launch_bounds__(256) k_classify(const float4* __restrict__ iou_max4,
                                                  const u64* __restrict__ colred,
                                                  const float4* __restrict__ rneg4,
                                                  u32* __restrict__ class32,
                                                  int* __restrict__ bcp, int* __restrict__ bcn) {
    __shared__ int wnr[T_N];
    int n = blockIdx.y;
    int bx = blockIdx.x;
    int tid = threadIdx.x;
    if (tid < T_N) wnr[tid] = (int)(~(u32)(colred[n * T_N + tid] & 0xFFFFFFFFull));
    __syncthreads();

    size_t gi4 = ((size_t)n * A_N) / 4 + bx * 256 + tid;
    float4 im = iou_max4[gi4];
    float4 rn = rneg4[gi4];
    int a0 = (bx * 256 + tid) * 4;

    u32 marked = 0;
#pragma unroll
    for (int t = 0; t < T_N; t++) {
        u32 d = (u32)(wnr[t] - a0);
        if (d < 4u) marked |= 1u << d;
    }

    float imv[4] = {im.x, im.y, im.z, im.w};
    float rnv[4] = {rn.x, rn.y, rn.z, rn.w};
    int pcnt = 0, ncnt = 0;
    u32 cw = 0;
#pragma unroll
    for (int j = 0; j < 4; j++) {
        int c = -1;
        if (imv[j] < 0.3f) c = 0;
        if ((marked >> j) & 1) c = 1;
        if (imv[j] >= 0.7f) c = 1;
        cw |= ((u32)(unsigned char)(signed char)c) << (8 * j);
        pcnt += (c == 1);
        ncnt += (c == 0 && rnv[j] < NEG_TAU);
    }
    class32[gi4] = cw;

#pragma unroll
    for (int off = 32; off > 0; off >>= 1) {
        pcnt += __shfl_xor(pcnt, off, 64);
        ncnt += __shfl_xor(ncnt, off, 64);
    }
    __shared__ int wp[4], wn[4];
    if ((tid & 63) == 0) { wp[tid >> 6] = pcnt; wn[tid >> 6] = ncnt; }
    __syncthreads();
    if (tid == 0) {
        bcp[n * BLK_C + bx] = wp[0] + wp[1] + wp[2] + wp[3];
        bcn[n * BLK_C + bx] = wn[0] + wn[1] + wn[2] + wn[3];
    }
}

// ---------------- gather: self-scan of block counts + dense candidate lists ----------------
__global__ void __launch_bounds__(256) k_gather(const u32* __restrict__ class32,
                                                const float4* __restrict__ rpos4,
                                                const float4* __restrict__ rneg4,
                                                const int* __restrict__ bcp,
                                                const int* __restrict__ bcn,
                                                u64* __restrict__ pos_list,
                                                u64* __restrict__ neg_list) {
    __shared__ int sp[BLK_C], sn[BLK_C];
    __shared__ int lp, ln;
    int n = blockIdx.y;
    int bx = blockIdx.x;
    int tid = threadIdx.x;
    if (tid == 0) { lp = 0; ln = 0; }
    if (tid < BLK_C) { sp[tid] = bcp[n * BLK_C + tid]; sn[tid] = bcn[n * BLK_C + tid]; }
    __syncthreads();
    for (int d = 1; d < BLK_C; d <<= 1) {
        int vp = 0, vn = 0;
        if (tid < BLK_C && tid >= d) { vp = sp[tid - d]; vn = sn[tid - d]; }
        __syncthreads();
        if (tid < BLK_C) { sp[tid] += vp; sn[tid] += vn; }
        __syncthreads();
    }
    int bp = bx ? sp[bx - 1] : 0;
    int bn = bx ? sn[bx - 1] : 0;

    size_t gi4 = ((size_t)n * A_N) / 4 + bx * 256 + tid;
    u32 cw = class32[gi4];
    float4 rp = rpos4[gi4];
    float4 rn = rneg4[gi4];
    float rpv[4] = {rp.x, rp.y, rp.z, rp.w};
    float rnv[4] = {rn.x, rn.y, rn.z, rn.w};
    int a0 = (bx * 256 + tid) * 4;

#pragma unroll
    for (int j = 0; j < 4; j++) {
        int c = (int)(signed char)((cw >> (8 * j)) & 0xFF);
        int a = a0 + j;
        if (c == 1) {
            int slot = atomicAdd(&lp, 1);
            int i = bp + slot;
            if (i < POS_CAP)
                pos_list[n * POS_CAP + i] = ((u64)__float_as_uint(rpv[j]) << 32) | (u32)a;
        } else if (c == 0 && rnv[j] < NEG_TAU) {
            int slot = atomicAdd(&ln, 1);
            int i = bn + slot;
            if (i < NEG_CAP)
                neg_list[n * NEG_CAP + i] = ((u64)__float_as_uint(rnv[j]) << 32) | (u32)a;
        }
    }
}

// ---------------- exact k-th smallest packed value (block-cooperative) ----------------
__device__ u64 select_kth(const u64* list, int cnt, int k, float scale, u64 overflow_cutoff,
                          int* hist, int* csum, u64* items, int* misc, u64* result) {
    int tid = threadIdx.x;
    if (k >= cnt) return overflow_cutoff;  // uniform

    for (int i = tid; i < NB; i += 256) hist[i] = 0;
    if (tid == 0) { misc[0] = -1; misc[1] = 0; misc[2] = 0; *result = overflow_cutoff; }
    __syncthreads();

    for (int i = tid; i < cnt; i += 256) {
        float v = __uint_as_float((u32)(list[i] >> 32));
        int b = (int)(v * scale); b = b < NB - 1 ? b : NB - 1;
        atomicAdd(&hist[b], 1);
    }
    __syncthreads();

    int base = tid * (NB / 256);
    int s = 0;
#pragma unroll
    for (int j = 0; j < NB / 256; j++) s += hist[base + j];
    csum[tid] = s;
    __syncthreads();
    if (tid == 0) {
        int run = 0;
        for (int j = 0; j < 256; j++) { int t = csum[j]; csum[j] = run; run += t; }
    }
    __syncthreads();
    int run = csum[tid];
#pragma unroll
    for (int j = 0; j < NB / 256; j++) {
        int h = hist[base + j];
        if (k >= run && k < run + h) { misc[0] = base + j; misc[1] = run; }
        run += h;
    }
    __syncthreads();
    int b = misc[0], before = misc[1];

    for (int i = tid; i < cnt; i += 256) {
        u64 p = list[i];
        float v = __uint_as_float((u32)(p >> 32));
        int bb = (int)(v * scale); bb = bb < NB - 1 ? bb : NB - 1;
        if (bb == b) { int ix = atomicAdd(&misc[2], 1); if (ix < ITEM_CAP) items[ix] = p; }
    }
    __syncthreads();
    int m = misc[2]; m = m < ITEM_CAP ? m : ITEM_CAP;
    int target = k - before;
    for (int i = tid; i < m; i += 256) {
        u64 p = items[i];
        int r = 0;
        for (int j = 0; j < m; j++) r += (items[j] < p);
        if (r == target) *result = p;
    }
    __syncthreads();
    u64 res = *result;
    __syncthreads();
    return res;
}

__global__ void k_select(const u64* __restrict__ pos_list, const u64* __restrict__ neg_list,
                         const int* __restrict__ bcp, const int* __restrict__ bcn,
                         u64* __restrict__ cutoff) {
    __shared__ int hist[NB];
    __shared__ int csum[256];
    __shared__ u64 items[ITEM_CAP];
    __shared__ int misc[4];
    __shared__ u64 result;
    __shared__ int pw[4], nw[4];
    int n = blockIdx.x;
    int tid = threadIdx.x;

    int pv = (tid < BLK_C) ? bcp[n * BLK_C + tid] : 0;
    int nv = (tid < BLK_C) ? bcn[n * BLK_C + tid] : 0;
#pragma unroll
    for (int off = 32; off > 0; off >>= 1) {
        pv += __shfl_xor(pv, off, 64);
        nv += __shfl_xor(nv, off, 64);
    }
    if ((tid & 63) == 0) { pw[tid >> 6] = pv; nw[tid >> 6] = nv; }
    __syncthreads();
    int P = pw[0] + pw[1] + pw[2] + pw[3];
    int C = nw[0] + nw[1] + nw[2] + nw[3];
    int Pc = P < POS_CAP ? P : POS_CAP;
    int Cc = C < NEG_CAP ? C : NEG_CAP;

    u64 cpos = select_kth(pos_list + n * POS_CAP, Pc, NUM_TRAIN / 2, (float)NB,
                          0xFFFFFFFFFFFFFFFFull, hist, csum, items, misc, &result);
    int n_pos = P < NUM_TRAIN / 2 ? P : NUM_TRAIN / 2;
    int k_neg = NUM_TRAIN - n_pos;
    u64 cneg = select_kth(neg_list + n * NEG_CAP, Cc, k_neg, (float)NB / NEG_TAU,
                          ((u64)__float_as_uint(NEG_TAU) << 32), hist, csum, items, misc, &result);
    if (tid == 0) { cutoff[2 * n] = cpos; cutoff[2 * n + 1] = cneg; }
}

// ---------------- final: subsample decision + deltas + output ----------------
__global__ void __launch_bounds__(256) k_final(const float4* __restrict__ anchors4,
                                               const float* __restrict__ gts,
                                               const u32* __restrict__ class32,
                                               const int4* __restrict__ best_gt4,
                                               const float4* __restrict__ rpos4,
                                               const float4* __restrict__ rneg4,
                                               const u64* __restrict__ cutoff,
                                               float4* __restrict__ out_classes4,
                                               float4* __restrict__ out_deltas) {
    __shared__ float g[T_N * 4];
    int n = blockIdx.y;
    int bx = blockIdx.x;
    int tid = threadIdx.x;
    g[tid] = gts[n * T_N * 4 + tid];
    __syncthreads();

    size_t gi4 = ((size_t)n * A_N) / 4 + bx * 256 + tid;
    u32 cw = class32[gi4];
    float4 rp = rpos4[gi4];
    float4 rn = rneg4[gi4];
    int4 bg4 = best_gt4[gi4];
    float rpv[4] = {rp.x, rp.y, rp.z, rp.w};
    float rnv[4] = {rn.x, rn.y, rn.z, rn.w};
    int bgv[4] = {bg4.x, bg4.y, bg4.z, bg4.w};
    int a0 = (bx * 256 + tid) * 4;
    u64 cp = cutoff[2 * n], cn = cutoff[2 * n + 1];

    float fcv[4];
#pragma unroll
    for (int j = 0; j < 4; j++) {
        int c = (int)(signed char)((cw >> (8 * j)) & 0xFF);
        int a = a0 + j;
        int fc = -1;
        if (c == 1) {
            u64 p = ((u64)__float_as_uint(rpv[j]) << 32) | (u32)a;
            fc = (p < cp) ? 1 : -1;
        } else if (c == 0) {
            u64 p = ((u64)__float_as_uint(rnv[j]) << 32) | (u32)a;
            fc = (p < cn) ? 0 : -1;
        }
        fcv[j] = (float)fc;

        float4 d = make_float4(0.f, 0.f, 0.f, 0.f);
        if (fc == 1) {
            float4 ab = anchors4[(size_t)n * A_N + a];
            float ay1 = ab.x, ax1 = ab.y, ay2 = ab.z, ax2 = ab.w;
            bool inb = (ay1 >= 0.f) && (ax1 >= 0.f) && (ay2 <= 1.f) && (ax2 <= 1.f);
            if (!inb) { ay1 = ax1 = ay2 = ax2 = 0.f; }
            int bg = bgv[j];
            float gy1 = g[bg * 4 + 0], gx1 = g[bg * 4 + 1];
            float gy2 = g[bg * 4 + 2], gx2 = g[bg * 4 + 3];
            float ah = ay2 - ay1, aw = ax2 - ax1;
            float acy = ay1 + 0.5f * ah, acx = ax1 + 0.5f * aw;
            float gh = gy2 - gy1, gw = gx2 - gx1;
            float gcy = gy1 + 0.5f * gh, gcx = gx1 + 0.5f * gw;
            float ah_s = ah > 0.f ? ah : 1.f, aw_s = aw > 0.f ? aw : 1.f;
            float gh_s = gh > 0.f ? gh : 1.f, gw_s = gw > 0.f ? gw : 1.f;
            d.x = (gcy - acy) / ah_s;
            d.y = (gcx - acx) / aw_s;
            d.z = logf(gh_s / ah_s);
            d.w = logf(gw_s / aw_s);
        }
        out_deltas[(size_t)n * A_N + a] = d;
    }
    out_classes4[gi4] = make_float4(fcv[0], fcv[1], fcv[2], fcv[3]);
}

extern "C" void kernel_launch(void* const* d_in, const int* in_sizes, int n_in,
                              void* d_out, int out_size, void* d_ws, size_t ws_size,
                              hipStream_t stream) {
    const float* anchors = (const float*)d_in[0];
    const float* gts     = (const float*)d_in[1];
    const float* rpos    = (const float*)d_in[2];
    const float* rneg    = (const float*)d_in[3];

    char* p = (char*)d_ws;
    u64* cutoff   = (u64*)p;  p += 2 * N_B * sizeof(u64);
    u64* colred   = (u64*)p;  p += N_B * T_N * sizeof(u64);
    u64* colpart  = (u64*)p;  p += (size_t)N_B * T_N * GBLK * sizeof(u64);
    u64* pos_list = (u64*)p;  p += (size_t)N_B * POS_CAP * sizeof(u64);
    u64* neg_list = (u64*)p;  p += (size_t)N_B * NEG_CAP * sizeof(u64);
    float* iou_max = (float*)p; p += (size_t)N_B * A_N * sizeof(float);
    int* best_gt   = (int*)p;   p += (size_t)N_B * A_N * sizeof(int);
    u32* class_tmp = (u32*)p;   p += (size_t)N_B * A_N;   // 1 byte per anchor
    int* bcp  = (int*)p;  p += N_B * BLK_C * sizeof(int);
    int* bcn  = (int*)p;  p += N_B * BLK_C * sizeof(int);

    float* out_classes = (float*)d_out;
    float4* out_deltas = (float4*)(out_classes + (size_t)N_B * A_N);

    k_main<<<dim3(GBLK, N_B), 256, 0, stream>>>(
        (const float4*)anchors, (const float4*)gts, iou_max, best_gt, colpart);
    k_colred<<<2, 256, 0, stream>>>(colpart, colred);
    k_classify<<<dim3(BLK_C, N_B), 256, 0, stream>>>(
        (const float4*)iou_max, colred, (const float4*)rneg, class_tmp, bcp, bcn);
    k_gather<<<dim3(BLK_C, N_B), 256, 0, stream>>>(
        class_tmp, (const float4*)rpos, (const float4*)rneg, bcp, bcn, pos_list, neg_list);
    k_select<<<N_B, 256, 0, stream>>>(pos_list, neg_list, bcp, bcn, cutoff);
    k_final<<<dim3(BLK_C, N_B), 256, 0, stream>>>(
        (const float4*)anchors, gts, class_tmp, (const int4*)best_gt,
        (const float4*)rpos, (const float4*)rneg, cutoff,
        (float4*)out_classes, out_deltas);
}

// Round 5
// 187.619 us; speedup vs baseline: 2.7360x; 1.1302x over previous
//
#include <hip/hip_runtime.h>
#include <stdint.h>

#define N_B 8
#define A_N 131072
#define T_N 64
#define NUM_TRAIN 256
#define POS_CAP 65536
#define NEG_CAP 32768
#define NEG_TAU 0.05f
#define NB2 256
#define ITEM_CAP 1024
#define APT 4
#define GBLK (A_N / (256 * APT))   // 128 k_main blocks per batch
#define BLK_C (A_N / (256 * 4))    // 128 classify/gather/final blocks per batch

typedef unsigned long long u64;
typedef unsigned int u32;

// IoU exactly matching the reference op sequence (no FMA contraction).
__device__ __forceinline__ float iou_one(float ay1, float ax1, float ay2, float ax2,
                                         float a_area, float gy1, float gx1, float gy2,
                                         float gx2, float g_area) {
#pragma clang fp contract(off)
    float ih = fmaxf(fminf(ay2, gy2) - fmaxf(ay1, gy1), 0.0f);
    float iw = fmaxf(fminf(ax2, gx2) - fmaxf(ax1, gx1), 0.0f);
    float inter = ih * iw;
    float uni = (a_area + g_area) - inter;
    return uni > 0.0f ? inter / uni : 0.0f;
}

// ---------------- main: row max value (-> preclass byte) + per-gt per-block column argmax ------
// Lane-staggered columns: at step jj all 64 lanes hit DISTINCT cmax[j] -> one no-return LDS
// atomicMax per thread per step, no shuffle butterfly, no dependent waitcnt chain (round-4 stall).
__global__ void __launch_bounds__(256, 4) k_main(const float4* __restrict__ anchors4,
                                                 const float4* __restrict__ gts4,
                                                 unsigned char* __restrict__ preclass,
                                                 u64* __restrict__ colpart) {
    __shared__ float4 gbox[T_N];
    __shared__ float gars[T_N];
    __shared__ u64 cmax[T_N];
    int n = blockIdx.y, tid = threadIdx.x, lane = tid & 63;
    int a0 = blockIdx.x * (256 * APT) + tid;
    if (tid < T_N) {
        float4 gb = gts4[n * T_N + tid];
        gbox[tid] = gb;
        {
#pragma clang fp contract(off)
            gars[tid] = (gb.z - gb.x) * (gb.w - gb.y);
        }
        cmax[tid] = 0xFFFFFFFFull;   // pack(v=0, anchor 0): first-index fallback
    }
    __syncthreads();

    float ay1[APT], ax1[APT], ay2[APT], ax2[APT], aar[APT], vmax[APT];
#pragma unroll
    for (int k = 0; k < APT; k++) {
        float4 ab = anchors4[(size_t)n * A_N + a0 + k * 256];
        float y1 = ab.x, x1 = ab.y, y2 = ab.z, x2 = ab.w;
        bool inb = (y1 >= 0.f) && (x1 >= 0.f) && (y2 <= 1.f) && (x2 <= 1.f);
        if (!inb) { y1 = x1 = y2 = x2 = 0.f; }
        ay1[k] = y1; ax1[k] = x1; ay2[k] = y2; ax2[k] = x2;
        {
#pragma clang fp contract(off)
            aar[k] = (y2 - y1) * (x2 - x1);
        }
        vmax[k] = 0.f;
    }

#pragma unroll 2
    for (int jj = 0; jj < T_N; jj++) {
        int j = (lane + jj) & (T_N - 1);
        float4 gb = gbox[j];
        float gar = gars[j];
        u64 colc = 0;
#pragma unroll
        for (int k = 0; k < APT; k++) {
            float v = iou_one(ay1[k], ax1[k], ay2[k], ax2[k], aar[k],
                              gb.x, gb.y, gb.z, gb.w, gar);
            vmax[k] = fmaxf(vmax[k], v);   // max of fl values == fl of max rational
            u64 pcv = ((u64)__float_as_uint(v) << 32) | (u32)(~(u32)(a0 + k * 256));
            colc = pcv > colc ? pcv : colc;   // v-desc, then anchor-asc (first-index ties)
        }
        atomicMax(&cmax[j], colc);   // distinct j per lane: zero same-address contention
    }

#pragma unroll
    for (int k = 0; k < APT; k++) {
        float vm = vmax[k];
        int c0 = (vm < 0.3f) ? 0 : ((vm >= 0.7f) ? 1 : -1);
        preclass[(size_t)n * A_N + a0 + k * 256] = (unsigned char)(signed char)c0;
    }
    __syncthreads();
    if (tid < T_N) colpart[((size_t)n * T_N + tid) * GBLK + blockIdx.x] = cmax[tid];
}

// ---------------- reduce per-block column partials -> winner anchor per (n,t) ----------------
__global__ void k_colred(const u64* __restrict__ colpart, int* __restrict__ wnr) {
    int w = blockIdx.x * 4 + (threadIdx.x >> 6);   // one wave per (n,t), 512 waves
    int lane = threadIdx.x & 63;
    const u64* p = colpart + (size_t)w * GBLK;
    u64 m = p[lane];
    u64 m2 = p[lane + 64];
    m = m2 > m ? m2 : m;
#pragma unroll
    for (int off = 32; off > 0; off >>= 1) {
        u64 o = (u64)__shfl_xor((unsigned long long)m, off, 64);
        m = o > m ? o : m;
    }
    if (lane == 0) wnr[w] = (int)(~(u32)(m & 0xFFFFFFFFull));
}

// ---------------- classify: final class bytes + per-block candidate counts ----------------
__global__ void __launch_bounds__(256) k_classify(const u32* __restrict__ preclass32,
                                                  const int* __restrict__ wnr,
                                                  const float4* __restrict__ rneg4,
                                                  u32* __restrict__ class32,
                                                  int* __restrict__ bcp, int* __restrict__ bcn) {
    __shared__ int wnrs[T_N];
    __shared__ int wp[4], wn[4];
    int n = blockIdx.y, bx = blockIdx.x, tid = threadIdx.x;
    if (tid < T_N) wnrs[tid] = wnr[n * T_N + tid];
    __syncthreads();

    size_t gi4 = ((size_t)n * A_N) / 4 + bx * 256 + tid;
    u32 pcw = preclass32[gi4];
    float4 rn = rneg4[gi4];
    int a0 = (bx * 256 + tid) * 4;

    u32 marked = 0;
#pragma unroll
    for (int t = 0; t < T_N; t++) {
        u32 d = (u32)(wnrs[t] - a0);
        if (d < 4u) marked |= 1u << d;
    }

    float rnv[4] = {rn.x, rn.y, rn.z, rn.w};
    int pcnt = 0, ncnt = 0;
    u32 cw = 0;
#pragma unroll
    for (int j = 0; j < 4; j++) {
        int c = (int)(signed char)((pcw >> (8 * j)) & 0xFF);
        if ((marked >> j) & 1) c = 1;   // col winner overrides 0/-1 (0.7-rule already 1)
        cw |= ((u32)(unsigned char)(signed char)c) << (8 * j);
        pcnt += (c == 1);
        ncnt += (c == 0 && rnv[j] < NEG_TAU);
    }
    class32[gi4] = cw;

#pragma unroll
    for (int off = 32; off > 0; off >>= 1) {
        pcnt += __shfl_xor(pcnt, off, 64);
        ncnt += __shfl_xor(ncnt, off, 64);
    }
    if ((tid & 63) == 0) { wp[tid >> 6] = pcnt; wn[tid >> 6] = ncnt; }
    __syncthreads();
    if (tid == 0) {
        bcp[n * BLK_C + bx] = wp[0] + wp[1] + wp[2] + wp[3];
        bcn[n * BLK_C + bx] = wn[0] + wn[1] + wn[2] + wn[3];
    }
}

// ---------------- gather: self-scan of block counts + dense candidate lists ----------------
__global__ void __launch_bounds__(256) k_gather(const u32* __restrict__ class32,
                                                const float4* __restrict__ rpos4,
                                                const float4* __restrict__ rneg4,
                                                const int* __restrict__ bcp,
                                                const int* __restrict__ bcn,
                                                u64* __restrict__ pos_list,
                                                u64* __restrict__ neg_list) {
    __shared__ int sp[BLK_C], sn[BLK_C];
    __shared__ int lp, ln;
    int n = blockIdx.y, bx = blockIdx.x, tid = threadIdx.x;
    if (tid == 0) { lp = 0; ln = 0; }
    if (tid < BLK_C) { sp[tid] = bcp[n * BLK_C + tid]; sn[tid] = bcn[n * BLK_C + tid]; }
    __syncthreads();
    for (int d = 1; d < BLK_C; d <<= 1) {
        int vp = 0, vn = 0;
        if (tid < BLK_C && tid >= d) { vp = sp[tid - d]; vn = sn[tid - d]; }
        __syncthreads();
        if (tid < BLK_C) { sp[tid] += vp; sn[tid] += vn; }
        __syncthreads();
    }
    int bp = bx ? sp[bx - 1] : 0;
    int bn = bx ? sn[bx - 1] : 0;

    size_t gi4 = ((size_t)n * A_N) / 4 + bx * 256 + tid;
    u32 cw = class32[gi4];
    float4 rp = rpos4[gi4];
    float4 rn = rneg4[gi4];
    float rpv[4] = {rp.x, rp.y, rp.z, rp.w};
    float rnv[4] = {rn.x, rn.y, rn.z, rn.w};
    int a0 = (bx * 256 + tid) * 4;

#pragma unroll
    for (int j = 0; j < 4; j++) {
        int c = (int)(signed char)((cw >> (8 * j)) & 0xFF);
        int a = a0 + j;
        if (c == 1) {
            int slot = atomicAdd(&lp, 1);
            int i = bp + slot;
            if (i < POS_CAP)
                pos_list[n * POS_CAP + i] = ((u64)__float_as_uint(rpv[j]) << 32) | (u32)a;
        } else if (c == 0 && rnv[j] < NEG_TAU) {
            int slot = atomicAdd(&ln, 1);
            int i = bn + slot;
            if (i < NEG_CAP)
                neg_list[n * NEG_CAP + i] = ((u64)__float_as_uint(rnv[j]) << 32) | (u32)a;
        }
    }
}

// ---------------- exact k-th smallest packed value (256 bins, parallel scan) ----------------
__device__ u64 select_kth(const u64* list, int cnt, int k, float scale, u64 ovf,
                          int* hist, u64* items, int* misc, u64* result, int* wsum) {
    int tid = threadIdx.x, lane = tid & 63, wid = tid >> 6;
    if (k >= cnt) return ovf;   // uniform decision across block

    hist[tid] = 0;
    if (tid == 0) { misc[0] = 0; *result = ovf; }
    __syncthreads();

    for (int i = tid; i < cnt; i += 256) {
        float v = __uint_as_float((u32)(list[i] >> 32));
        int b = (int)(v * scale); b = b < NB2 - 1 ? b : NB2 - 1;
        atomicAdd(&hist[b], 1);
    }
    __syncthreads();

    int h = hist[tid];
    int v = h;
#pragma unroll
    for (int d = 1; d < 64; d <<= 1) {
        int t = __shfl_up(v, d, 64);
        if (lane >= d) v += t;
    }
    if (lane == 63) wsum[wid] = v;
    __syncthreads();
    int base = 0;
    for (int w = 0; w < wid; w++) base += wsum[w];
    int incl = base + v, excl = incl - h;
    if (k >= excl && k < incl) { misc[1] = tid; misc[2] = excl; }
    __syncthreads();
    int b = misc[1], before = misc[2];

    for (int i = tid; i < cnt; i += 256) {
        u64 p = list[i];
        float vv = __uint_as_float((u32)(p >> 32));
        int bb = (int)(vv * scale); bb = bb < NB2 - 1 ? bb : NB2 - 1;
        if (bb == b) { int ix = atomicAdd(&misc[0], 1); if (ix < ITEM_CAP) items[ix] = p; }
    }
    __syncthreads();
    int m = misc[0]; m = m < ITEM_CAP ? m : ITEM_CAP;
    int target = k - before;
    for (int i = tid; i < m; i += 256) {
        u64 p = items[i];
        int r = 0;
        for (int j = 0; j < m; j++) r += (items[j] < p);
        if (r == target) *result = p;
    }
    __syncthreads();
    u64 res = *result;
    __syncthreads();
    return res;
}

__global__ void k_select(const u64* __restrict__ pos_list, const u64* __restrict__ neg_list,
                         const int* __restrict__ bcp, const int* __restrict__ bcn,
                         u64* __restrict__ cutoff) {
    __shared__ int hist[NB2];
    __shared__ u64 items[ITEM_CAP];
    __shared__ int misc[3];
    __shared__ u64 result;
    __shared__ int wsum[4];
    __shared__ int pw[4], nw[4];
    int n = blockIdx.x, tid = threadIdx.x;

    int pv = (tid < BLK_C) ? bcp[n * BLK_C + tid] : 0;
    int nv = (tid < BLK_C) ? bcn[n * BLK_C + tid] : 0;
#pragma unroll
    for (int off = 32; off > 0; off >>= 1) {
        pv += __shfl_xor(pv, off, 64);
        nv += __shfl_xor(nv, off, 64);
    }
    if ((tid & 63) == 0) { pw[tid >> 6] = pv; nw[tid >> 6] = nv; }
    __syncthreads();
    int P = pw[0] + pw[1] + pw[2] + pw[3];
    int C = nw[0] + nw[1] + nw[2] + nw[3];
    int Pc = P < POS_CAP ? P : POS_CAP;
    int Cc = C < NEG_CAP ? C : NEG_CAP;

    u64 cpos = select_kth(pos_list + n * POS_CAP, Pc, NUM_TRAIN / 2, (float)NB2,
                          0xFFFFFFFFFFFFFFFFull, hist, items, misc, &result, wsum);
    int n_pos = P < NUM_TRAIN / 2 ? P : NUM_TRAIN / 2;
    int k_neg = NUM_TRAIN - n_pos;
    u64 cneg = select_kth(neg_list + n * NEG_CAP, Cc, k_neg, (float)NB2 / NEG_TAU,
                          ((u64)__float_as_uint(NEG_TAU) << 32), hist, items, misc, &result, wsum);
    if (tid == 0) { cutoff[2 * n] = cpos; cutoff[2 * n + 1] = cneg; }
}

// ---------------- final: subsample decision + exact best_gt recompute + deltas ----------------
__global__ void __launch_bounds__(256) k_final(const float4* __restrict__ anchors4,
                                               const float4* __restrict__ gts4,
                                               const u32* __restrict__ class32,
                                               const float4* __restrict__ rpos4,
                                               const float4* __restrict__ rneg4,
                                               const u64* __restrict__ cutoff,
                                               float4* __restrict__ out_classes4,
                                               float4* __restrict__ out_deltas) {
    __shared__ float4 gbox[T_N];
    __shared__ float gars[T_N];
    int n = blockIdx.y, bx = blockIdx.x, tid = threadIdx.x;
    if (tid < T_N) {
        float4 gb = gts4[n * T_N + tid];
        gbox[tid] = gb;
        {
#pragma clang fp contract(off)
            gars[tid] = (gb.z - gb.x) * (gb.w - gb.y);
        }
    }
    __syncthreads();

    size_t gi4 = ((size_t)n * A_N) / 4 + bx * 256 + tid;
    u32 cw = class32[gi4];
    float4 rp = rpos4[gi4];
    float4 rn = rneg4[gi4];
    float rpv[4] = {rp.x, rp.y, rp.z, rp.w};
    float rnv[4] = {rn.x, rn.y, rn.z, rn.w};
    int a0 = (bx * 256 + tid) * 4;
    u64 cp = cutoff[2 * n], cn = cutoff[2 * n + 1];

    float fcv[4];
#pragma unroll
    for (int j = 0; j < 4; j++) {
        int c = (int)(signed char)((cw >> (8 * j)) & 0xFF);
        int a = a0 + j;
        int fc = -1;
        if (c == 1) {
            u64 p = ((u64)__float_as_uint(rpv[j]) << 32) | (u32)a;
            fc = (p < cp) ? 1 : -1;
        } else if (c == 0) {
            u64 p = ((u64)__float_as_uint(rnv[j]) << 32) | (u32)a;
            fc = (p < cn) ? 0 : -1;
        }
        fcv[j] = (float)fc;

        float4 d = make_float4(0.f, 0.f, 0.f, 0.f);
        if (fc == 1) {
            float4 ab = anchors4[(size_t)n * A_N + a];
            float ay1 = ab.x, ax1 = ab.y, ay2 = ab.z, ax2 = ab.w;
            bool inb = (ay1 >= 0.f) && (ax1 >= 0.f) && (ay2 <= 1.f) && (ax2 <= 1.f);
            if (!inb) { ay1 = ax1 = ay2 = ax2 = 0.f; }
            float a_area;
            {
#pragma clang fp contract(off)
                a_area = (ay2 - ay1) * (ax2 - ax1);
            }
            // exact best_gt: strict > keeps FIRST max index == jnp.argmax semantics
            float vm = 0.f; int jb = 0;
            for (int t = 0; t < T_N; t++) {
                float4 gb = gbox[t];
                float v = iou_one(ay1, ax1, ay2, ax2, a_area, gb.x, gb.y, gb.z, gb.w, gars[t]);
                bool g = v > vm;
                vm = g ? v : vm;
                jb = g ? t : jb;
            }
            float4 gb = gbox[jb];
            float gy1 = gb.x, gx1 = gb.y, gy2 = gb.z, gx2 = gb.w;
            float ah = ay2 - ay1, aw = ax2 - ax1;
            float acy = ay1 + 0.5f * ah, acx = ax1 + 0.5f * aw;
            float gh = gy2 - gy1, gw = gx2 - gx1;
            float gcy = gy1 + 0.5f * gh, gcx = gx1 + 0.5f * gw;
            float ah_s = ah > 0.f ? ah : 1.f, aw_s = aw > 0.f ? aw : 1.f;
            float gh_s = gh > 0.f ? gh : 1.f, gw_s = gw > 0.f ? gw : 1.f;
            d.x = (gcy - acy) / ah_s;
            d.y = (gcx - acx) / aw_s;
            d.z = logf(gh_s / ah_s);
            d.w = logf(gw_s / aw_s);
        }
        out_deltas[(size_t)n * A_N + a] = d;
    }
    out_classes4[gi4] = make_float4(fcv[0], fcv[1], fcv[2], fcv[3]);
}

extern "C" void kernel_launch(void* const* d_in, const int* in_sizes, int n_in,
                              void* d_out, int out_size, void* d_ws, size_t ws_size,
                              hipStream_t stream) {
    const float* anchors = (const float*)d_in[0];
    const float* gts     = (const float*)d_in[1];
    const float* rpos    = (const float*)d_in[2];
    const float* rneg    = (const float*)d_in[3];

    char* p = (char*)d_ws;
    u64* cutoff   = (u64*)p;  p += 2 * N_B * sizeof(u64);
    u64* colpart  = (u64*)p;  p += (size_t)N_B * T_N * GBLK * sizeof(u64);
    u64* pos_list = (u64*)p;  p += (size_t)N_B * POS_CAP * sizeof(u64);
    u64* neg_list = (u64*)p;  p += (size_t)N_B * NEG_CAP * sizeof(u64);
    u32* preclass = (u32*)p;  p += (size_t)N_B * A_N;     // 1 byte per anchor
    u32* class_f  = (u32*)p;  p += (size_t)N_B * A_N;     // 1 byte per anchor
    int* bcp  = (int*)p;  p += N_B * BLK_C * sizeof(int);
    int* bcn  = (int*)p;  p += N_B * BLK_C * sizeof(int);
    int* wnr  = (int*)p;  p += N_B * T_N * sizeof(int);

    float* out_classes = (float*)d_out;
    float4* out_deltas = (float4*)(out_classes + (size_t)N_B * A_N);

    k_main<<<dim3(GBLK, N_B), 256, 0, stream>>>(
        (const float4*)anchors, (const float4*)gts, (unsigned char*)preclass, colpart);
    k_colred<<<N_B * T_N / 4, 256, 0, stream>>>(colpart, wnr);
    k_classify<<<dim3(BLK_C, N_B), 256, 0, stream>>>(
        preclass, wnr, (const float4*)rneg, class_f, bcp, bcn);
    k_gather<<<dim3(BLK_C, N_B), 256, 0, stream>>>(
        class_f, (const float4*)rpos, (const float4*)rneg, bcp, bcn, pos_list, neg_list);
    k_select<<<N_B, 256, 0, stream>>>(pos_list, neg_list, bcp, bcn, cutoff);
    k_final<<<dim3(BLK_C, N_B), 256, 0, stream>>>(
        (const float4*)anchors, (const float4*)gts, class_f,
        (const float4*)rpos, (const float4*)rneg, cutoff,
        (float4*)out_classes, out_deltas);
}